// Round 2
// baseline (749.266 us; speedup 1.0000x reference)
//
#include <hip/hip_runtime.h>
#include <stdint.h>

#define S_LEN 2048
#define D_DIM 64
#define NQT   32          // q tiles of 64 rows
#define LOG2E 1.44269504088896f

typedef __attribute__((ext_vector_type(8))) short bf16x8;
typedef __attribute__((ext_vector_type(4))) short s16x4;
typedef __attribute__((ext_vector_type(4))) float f32x4;

__device__ __forceinline__ short f2bf(float f) {
    uint32_t u = __builtin_bit_cast(uint32_t, f);
    u += 0x7FFFu + ((u >> 16) & 1u);   // RNE
    return (short)(u >> 16);
}

// XOR swizzle on short-index of a [rows][64]-short LDS tile:
// byte ^= (row&7)<<4  ->  short_idx ^= (row&7)<<3.
// Keeps 8B/16B alignment (flips bits >=3); makes ds_read_b128 column reads
// and staging writes conflict-free (<=2-way).
__device__ __forceinline__ int swz(int row, int col) {
    return (row * 64 + col) ^ ((row & 7) << 3);
}

#if __has_builtin(__builtin_amdgcn_exp2f)
#define EXP2(x) __builtin_amdgcn_exp2f(x)
#else
#define EXP2(x) exp2f(x)
#endif

__global__ __launch_bounds__(256, 3)
void attn_fwd_kernel(const float* __restrict__ Q, const float* __restrict__ K,
                     const float* __restrict__ V, float* __restrict__ Out)
{
    const int pair = blockIdx.x;          // 0..15
    const int bh   = blockIdx.y;          // 0..63
    const int tid  = threadIdx.x;
    const int wid  = tid >> 6;
    const int lane = tid & 63;
    const int lq   = lane & 15;
    const int lg   = lane >> 4;

    const int qtA = NQT - 1 - pair;       // heavy q-tile (16..31)
    const int qtB = pair;                 // light q-tile (0..15)
    const int nkv = qtA + 1;              // kv tiles 0..qtA

    const size_t base = (size_t)bh * S_LEN * D_DIM;
    const float* Qp = Q + base;
    const float* Kp = K + base;
    const float* Vp = V + base;
    float*       Op = Out + base;

    __shared__ __align__(16) short Kl[2][64 * 64];   // K tile, bf16, swizzled
    __shared__ __align__(16) short Vl[2][64 * 64];   // V^T tile (d-major), bf16, swizzled
    __shared__ __align__(16) short Pl[4][16 * 64];   // per-wave P round-trip

    const int qw0A = qtA * 64 + wid * 16;
    const int qw0B = qtB * 64 + wid * 16;

    // ---- Q fragments for both q-tiles, pre-scaled by log2e/sqrt(D) ----
    bf16x8 qfA[2], qfB[2];
    {
        const float sc = 0.125f * LOG2E;
        #pragma unroll
        for (int c = 0; c < 2; ++c) {
            const float* pa = Qp + (size_t)(qw0A + lq) * D_DIM + c * 32 + lg * 8;
            const float* pb = Qp + (size_t)(qw0B + lq) * D_DIM + c * 32 + lg * 8;
            f32x4 a0 = *(const f32x4*)pa, a1 = *(const f32x4*)(pa + 4);
            f32x4 b0 = *(const f32x4*)pb, b1 = *(const f32x4*)(pb + 4);
            #pragma unroll
            for (int j = 0; j < 4; ++j) {
                qfA[c][j] = f2bf(a0[j] * sc); qfA[c][4 + j] = f2bf(a1[j] * sc);
                qfB[c][j] = f2bf(b0[j] * sc); qfB[c][4 + j] = f2bf(b1[j] * sc);
            }
        }
    }

    f32x4 accA[4], accB[4];
    float mA[4], lA[4], mB[4], lB[4];
    #pragma unroll
    for (int t = 0; t < 4; ++t) { accA[t] = (f32x4)0.f; accB[t] = (f32x4)0.f; }
    #pragma unroll
    for (int r = 0; r < 4; ++r) { mA[r] = -1e30f; lA[r] = 0.f; mB[r] = -1e30f; lB[r] = 0.f; }

    // staging registers: K coalesced row-major; V gathered column-wise so the
    // transpose WRITE is row-contiguous (conflict-free)
    f32x4 kreg[4], vreg[4];

#define ISSUE(kb) { \
        const float* kp_ = Kp + (size_t)(kb) * 64 * D_DIM; \
        const float* vp_ = Vp + (size_t)(kb) * 64 * D_DIM; \
        _Pragma("unroll") for (int it = 0; it < 4; ++it) { \
            int idx = tid + it * 256; \
            kreg[it] = *(const f32x4*)(kp_ + (idx >> 4) * D_DIM + (idx & 15) * 4); \
            vreg[it] = *(const f32x4*)(vp_ + lane * D_DIM + (wid + it * 4) * 4); \
        } }

#define WRITE_LDS(buf) { \
        _Pragma("unroll") for (int it = 0; it < 4; ++it) { \
            int idx = tid + it * 256; int row = idx >> 4, c4 = idx & 15; \
            s16x4 w; \
            _Pragma("unroll") for (int j = 0; j < 4; ++j) w[j] = f2bf(kreg[it][j]); \
            *(s16x4*)&Kl[buf][swz(row, c4 * 4)] = w; \
            int vr = (wid + it * 4) * 4; \
            _Pragma("unroll") for (int j = 0; j < 4; ++j) \
                Vl[buf][swz(vr + j, lane)] = f2bf(vreg[it][j]); \
        } }

    auto compute = [&](const bf16x8* qf, f32x4* acc, float* m, float* l,
                       int qw0, int kv0, int buf, bool domask) {
        f32x4 s[4];
        #pragma unroll
        for (int t = 0; t < 4; ++t) s[t] = (f32x4)0.f;
        // ---- QK^T from LDS ----
        #pragma unroll
        for (int t = 0; t < 4; ++t) {
            const int row = t * 16 + lq;
            #pragma unroll
            for (int c = 0; c < 2; ++c) {
                bf16x8 kf = *(const bf16x8*)&Kl[buf][swz(row, c * 32 + lg * 8)];
                s[t] = __builtin_amdgcn_mfma_f32_16x16x32_bf16(qf[c], kf, s[t], 0, 0, 0);
            }
        }
        if (domask) {
            #pragma unroll
            for (int t = 0; t < 4; ++t) {
                const int kvc = kv0 + t * 16 + lq;
                #pragma unroll
                for (int r = 0; r < 4; ++r)
                    if (kvc > qw0 + lg * 4 + r) s[t][r] = -1e30f;
            }
        }
        // ---- online softmax (log2 domain) ----
        #pragma unroll
        for (int r = 0; r < 4; ++r) {
            float v0 = fmaxf(fmaxf(s[0][r], s[1][r]), fmaxf(s[2][r], s[3][r]));
            v0 = fmaxf(v0, __shfl_xor(v0, 1));
            v0 = fmaxf(v0, __shfl_xor(v0, 2));
            v0 = fmaxf(v0, __shfl_xor(v0, 4));
            v0 = fmaxf(v0, __shfl_xor(v0, 8));
            const float mn = fmaxf(m[r], v0);
            const float f  = EXP2(m[r] - mn);
            m[r] = mn; l[r] *= f;
            #pragma unroll
            for (int t = 0; t < 4; ++t) acc[t][r] *= f;
        }
        #pragma unroll
        for (int t = 0; t < 4; ++t) {
            #pragma unroll
            for (int r = 0; r < 4; ++r) {
                float p = EXP2(s[t][r] - m[r]);
                s[t][r] = p;
                const int prow = lg * 4 + r;
                Pl[wid][swz(prow, t * 16 + lq)] = f2bf(p);
            }
        }
        #pragma unroll
        for (int r = 0; r < 4; ++r) {
            float rs = s[0][r] + s[1][r] + s[2][r] + s[3][r];
            rs += __shfl_xor(rs, 1);
            rs += __shfl_xor(rs, 2);
            rs += __shfl_xor(rs, 4);
            rs += __shfl_xor(rs, 8);
            l[r] += rs;
        }
        // ---- PV from LDS ----
        #pragma unroll
        for (int c = 0; c < 2; ++c) {
            bf16x8 pf = *(const bf16x8*)&Pl[wid][swz(lq, c * 32 + lg * 8)];
            #pragma unroll
            for (int t = 0; t < 4; ++t) {
                bf16x8 vf = *(const bf16x8*)&Vl[buf][swz(t * 16 + lq, c * 32 + lg * 8)];
                acc[t] = __builtin_amdgcn_mfma_f32_16x16x32_bf16(pf, vf, acc[t], 0, 0, 0);
            }
        }
    };

    // ---- main loop: double-buffered, prefetch next tile into registers ----
    ISSUE(0);
    WRITE_LDS(0);
    __syncthreads();

    for (int kb = 0; kb < nkv; ++kb) {
        const int buf = kb & 1;
        const bool more = (kb + 1) < nkv;
        if (more) ISSUE(kb + 1);                       // overlaps compute below
        compute(qfA, accA, mA, lA, qw0A, kb * 64, buf, kb == qtA);
        if (kb <= qtB)
            compute(qfB, accB, mB, lB, qw0B, kb * 64, buf, kb == qtB);
        __syncthreads();                               // all reads of buf^1 done
        if (more) WRITE_LDS(buf ^ 1);
        __syncthreads();                               // next tile visible
    }

    // ---- epilogue ----
    #pragma unroll
    for (int r = 0; r < 4; ++r) {
        const float ia = 1.f / lA[r];
        const float ib = 1.f / lB[r];
        #pragma unroll
        for (int t = 0; t < 4; ++t) {
            Op[(size_t)(qw0A + lg * 4 + r) * D_DIM + t * 16 + lq] = accA[t][r] * ia;
            Op[(size_t)(qw0B + lg * 4 + r) * D_DIM + t * 16 + lq] = accB[t][r] * ib;
        }
    }
}

extern "C" void kernel_launch(void* const* d_in, const int* in_sizes, int n_in,
                              void* d_out, int out_size, void* d_ws, size_t ws_size,
                              hipStream_t stream) {
    const float* q = (const float*)d_in[0];
    const float* k = (const float*)d_in[1];
    const float* v = (const float*)d_in[2];
    // d_in[3] (causal tril mask) handled analytically.
    float* out = (float*)d_out;
    (void)d_ws; (void)ws_size; (void)in_sizes; (void)n_in; (void)out_size;

    dim3 grid(NQT / 2, 4 * 16 /* B*H */);
    dim3 block(256);
    attn_fwd_kernel<<<grid, block, 0, stream>>>(q, k, v, out);
}

// Round 3
// 365.408 us; speedup vs baseline: 2.0505x; 2.0505x over previous
//
#include <hip/hip_runtime.h>
#include <stdint.h>

#define S_LEN 2048
#define D_DIM 64
#define NQT   32
#define LOG2E 1.44269504088896f
#define THR   8.0f

typedef __attribute__((ext_vector_type(8))) short bf16x8;
typedef __attribute__((ext_vector_type(4))) short s16x4;
typedef __attribute__((ext_vector_type(4))) float f32x4;

__device__ __forceinline__ short f2bf(float f) {
    uint32_t u = __builtin_bit_cast(uint32_t, f);
    u += 0x7FFFu + ((u >> 16) & 1u);   // RNE
    return (short)(u >> 16);
}

// XOR swizzle on short-index of a [rows][64]-short LDS tile.
// Flips short-bits 3..5 (byte bits 4..6): preserves 8B/16B alignment and
// keeps 4/8-short blocks contiguous; spreads banks for strided access.
__device__ __forceinline__ int swz(int row, int col) {
    return (row * 64 + col) ^ ((row & 7) << 3);
}

#if __has_builtin(__builtin_amdgcn_exp2f)
#define EXP2(x) __builtin_amdgcn_exp2f(x)
#else
#define EXP2(x) exp2f(x)
#endif

// ---- staging: coalesced global reads into regs (issued early) ----
#define ISSUE(kb) do { \
    const float* kp_ = Kp + (size_t)(kb) * 64 * D_DIM; \
    const float* vp_ = Vp + (size_t)(kb) * 64 * D_DIM; \
    _Pragma("unroll") for (int it = 0; it < 4; ++it) { \
        const int idx_ = tid + it * 256; \
        kreg[it] = *(const f32x4*)(kp_ + (idx_ >> 4) * D_DIM + (idx_ & 15) * 4); \
        vreg[it] = *(const f32x4*)(vp_ + (idx_ >> 4) * D_DIM + (idx_ & 15) * 4); \
    } \
} while (0)

// ---- staging: convert + write LDS (K row-major, V transposed) ----
#define WRITE_LDS(b) do { \
    _Pragma("unroll") for (int it = 0; it < 4; ++it) { \
        const int idx_ = tid + it * 256; \
        const int row_ = idx_ >> 4, c4_ = idx_ & 15; \
        s16x4 w_; \
        _Pragma("unroll") for (int j = 0; j < 4; ++j) w_[j] = f2bf(kreg[it][j]); \
        *(s16x4*)&Kl[b][swz(row_, c4_ * 4)] = w_; \
        _Pragma("unroll") for (int j = 0; j < 4; ++j) \
            Vl[b][swz(c4_ * 4 + j, row_)] = f2bf(vreg[it][j]); \
    } \
} while (0)

// Swapped QK^T: s_[t][r] = S[kv = kv0+t*16+lg*4+r][q = qw0+lq].
// All 16 scores in a lane belong to q-row lq -> softmax = in-lane reduce + 2 shfl.
// PV output: acc[t][r] = O[q = qw0+lg*4+r][d = t*16+lq].
#define COMPUTE(qf, acc, mm, ll, qw0, kv0, b, domask) do { \
    f32x4 s_[4]; \
    _Pragma("unroll") for (int t = 0; t < 4; ++t) s_[t] = (f32x4)0.f; \
    _Pragma("unroll") for (int t = 0; t < 4; ++t) { \
        _Pragma("unroll") for (int c = 0; c < 2; ++c) { \
            bf16x8 kf_ = *(const bf16x8*)&Kl[b][swz(t * 16 + lq, c * 32 + lg * 8)]; \
            s_[t] = __builtin_amdgcn_mfma_f32_16x16x32_bf16(kf_, qf[c], s_[t], 0, 0, 0); \
        } \
    } \
    if (domask) { \
        _Pragma("unroll") for (int t = 0; t < 4; ++t) \
            _Pragma("unroll") for (int r = 0; r < 4; ++r) \
                if ((kv0) + t * 16 + lg * 4 + r > (qw0) + lq) s_[t][r] = -1e30f; \
    } \
    float pmax_ = s_[0][0]; \
    _Pragma("unroll") for (int t = 0; t < 4; ++t) \
        _Pragma("unroll") for (int r = 0; r < 4; ++r) \
            if (t | r) pmax_ = fmaxf(pmax_, s_[t][r]); \
    pmax_ = fmaxf(pmax_, __shfl_xor(pmax_, 16)); \
    pmax_ = fmaxf(pmax_, __shfl_xor(pmax_, 32)); \
    if (!__all(pmax_ <= (mm) + THR)) {           /* defer-max: rare rescale */ \
        const float mn_ = fmaxf((mm), pmax_); \
        const float f_  = EXP2((mm) - mn_); \
        (ll) *= f_; \
        _Pragma("unroll") for (int r = 0; r < 4; ++r) { \
            const float fr_ = __shfl(f_, lg * 4 + r); \
            _Pragma("unroll") for (int t = 0; t < 4; ++t) acc[t][r] *= fr_; \
        } \
        (mm) = mn_; \
    } \
    float rs_ = 0.f; \
    _Pragma("unroll") for (int t = 0; t < 4; ++t) { \
        s16x4 pw_; \
        _Pragma("unroll") for (int r = 0; r < 4; ++r) { \
            const float p_ = EXP2(s_[t][r] - (mm)); \
            rs_ += p_; \
            pw_[r] = f2bf(p_); \
        } \
        *(s16x4*)&Pl[wid][swz(lq, t * 16 + lg * 4)] = pw_; \
    } \
    rs_ += __shfl_xor(rs_, 16); \
    rs_ += __shfl_xor(rs_, 32); \
    (ll) += rs_; \
    _Pragma("unroll") for (int c = 0; c < 2; ++c) { \
        bf16x8 pf_ = *(const bf16x8*)&Pl[wid][swz(lq, c * 32 + lg * 8)]; \
        _Pragma("unroll") for (int t = 0; t < 4; ++t) { \
            bf16x8 vf_ = *(const bf16x8*)&Vl[b][swz(t * 16 + lq, c * 32 + lg * 8)]; \
            acc[t] = __builtin_amdgcn_mfma_f32_16x16x32_bf16(pf_, vf_, acc[t], 0, 0, 0); \
        } \
    } \
} while (0)

__global__ __launch_bounds__(256, 4)
void attn_fwd_kernel(const float* __restrict__ Q, const float* __restrict__ K,
                     const float* __restrict__ V, float* __restrict__ Out)
{
    const int bh   = blockIdx.x;          // 0..63  (fast dim -> heavy pairs dispatch first)
    const int pair = blockIdx.y;          // 0..15
    const int tid  = threadIdx.x;
    const int wid  = tid >> 6;
    const int lane = tid & 63;
    const int lq   = lane & 15;
    const int lg   = lane >> 4;

    const int qtA = NQT - 1 - pair;       // heavy q-tile (16..31)
    const int qtB = pair;                 // light q-tile (0..15); A-tiles + B-tiles = 33 computes/block
    const int nkv = qtA + 1;

    const size_t base = (size_t)bh * S_LEN * D_DIM;
    const float* Qp = Q + base;
    const float* Kp = K + base;
    const float* Vp = V + base;
    float*       Op = Out + base;

    __shared__ __align__(16) short Kl[2][64 * 64];   // K tile [kv][d], bf16, swizzled
    __shared__ __align__(16) short Vl[2][64 * 64];   // V^T tile [d][kv], bf16, swizzled
    __shared__ __align__(16) short Pl[4][16 * 64];   // per-wave P [q][kv], bf16, swizzled

    const int qw0A = qtA * 64 + wid * 16;
    const int qw0B = qtB * 64 + wid * 16;

    // Q fragments (B-operand of swapped QK^T), pre-scaled by log2e/sqrt(D)
    bf16x8 qfA[2], qfB[2];
    {
        const float sc = 0.125f * LOG2E;
        #pragma unroll
        for (int c = 0; c < 2; ++c) {
            const float* pa = Qp + (size_t)(qw0A + lq) * D_DIM + c * 32 + lg * 8;
            const float* pb = Qp + (size_t)(qw0B + lq) * D_DIM + c * 32 + lg * 8;
            f32x4 a0 = *(const f32x4*)pa, a1 = *(const f32x4*)(pa + 4);
            f32x4 b0 = *(const f32x4*)pb, b1 = *(const f32x4*)(pb + 4);
            #pragma unroll
            for (int j = 0; j < 4; ++j) {
                qfA[c][j] = f2bf(a0[j] * sc); qfA[c][4 + j] = f2bf(a1[j] * sc);
                qfB[c][j] = f2bf(b0[j] * sc); qfB[c][4 + j] = f2bf(b1[j] * sc);
            }
        }
    }

    f32x4 accA[4], accB[4];
    #pragma unroll
    for (int t = 0; t < 4; ++t) { accA[t] = (f32x4)0.f; accB[t] = (f32x4)0.f; }
    float mA = -1e30f, lA = 0.f, mB = -1e30f, lB = 0.f;

    f32x4 kreg[4], vreg[4];

    ISSUE(0);
    WRITE_LDS(0);
    __syncthreads();

    for (int kb = 0; kb < nkv; ++kb) {
        const int  buf  = kb & 1;
        const bool more = (kb + 1) < nkv;
        if (more) ISSUE(kb + 1);                 // global loads overlap compute
        COMPUTE(qfA, accA, mA, lA, qw0A, kb * 64, buf, (kb == qtA));
        if (kb <= qtB)
            COMPUTE(qfB, accB, mB, lB, qw0B, kb * 64, buf, (kb == qtB));
        __syncthreads();                         // all reads of buf^1 done
        if (more) WRITE_LDS(buf ^ 1);
        __syncthreads();                         // next tile visible
    }

    // ---- epilogue: O[q][d] = acc / l(q) ----
    #pragma unroll
    for (int r = 0; r < 4; ++r) {
        const float lrA = __shfl(lA, lg * 4 + r);
        const float lrB = __shfl(lB, lg * 4 + r);
        const float iA = 1.f / lrA;
        const float iB = 1.f / lrB;
        #pragma unroll
        for (int t = 0; t < 4; ++t) {
            Op[(size_t)(qw0A + lg * 4 + r) * D_DIM + t * 16 + lq] = accA[t][r] * iA;
            Op[(size_t)(qw0B + lg * 4 + r) * D_DIM + t * 16 + lq] = accB[t][r] * iB;
        }
    }
}

extern "C" void kernel_launch(void* const* d_in, const int* in_sizes, int n_in,
                              void* d_out, int out_size, void* d_ws, size_t ws_size,
                              hipStream_t stream) {
    const float* q = (const float*)d_in[0];
    const float* k = (const float*)d_in[1];
    const float* v = (const float*)d_in[2];
    // d_in[3] (causal tril mask) handled analytically.
    float* out = (float*)d_out;
    (void)d_ws; (void)ws_size; (void)in_sizes; (void)n_in; (void)out_size;

    dim3 grid(4 * 16 /* B*H */, NQT / 2);
    dim3 block(256);
    attn_fwd_kernel<<<grid, block, 0, stream>>>(q, k, v, out);
}

// Round 5
// 120.861 us; speedup vs baseline: 6.1994x; 3.0234x over previous
//
#include <hip/hip_runtime.h>
#include <stdint.h>

#define S_LEN 2048
#define D_DIM 64
#define NQT   32
#define LOG2E 1.44269504088896f
#define THR   8.0f

typedef __attribute__((ext_vector_type(8))) short bf16x8;
typedef __attribute__((ext_vector_type(4))) short s16x4;
typedef __attribute__((ext_vector_type(4))) float f32x4;

__device__ __forceinline__ short f2bf(float f) {
    uint32_t u = __builtin_bit_cast(uint32_t, f);
    u += 0x7FFFu + ((u >> 16) & 1u);   // RNE
    return (short)(u >> 16);
}

// XOR swizzle on short-index of a [rows][64]-short LDS tile.
// Flips short-bits 3..5 (byte bits 4..6): preserves 8B/16B alignment.
__device__ __forceinline__ int swz(int row, int col) {
    return (row * 64 + col) ^ ((row & 7) << 3);
}

#if __has_builtin(__builtin_amdgcn_exp2f)
#define EXP2(x) __builtin_amdgcn_exp2f(x)
#else
#define EXP2(x) exp2f(x)
#endif

// ---- staging: coalesced global reads into regs (issued early) ----
#define ISSUE(kb) do { \
    const float* kp_ = Kp + (size_t)(kb) * 64 * D_DIM; \
    const float* vp_ = Vp + (size_t)(kb) * 64 * D_DIM; \
    _Pragma("unroll") for (int it = 0; it < 4; ++it) { \
        const int idx_ = tid + it * 256; \
        kreg[it] = *(const f32x4*)(kp_ + (idx_ >> 4) * D_DIM + (idx_ & 15) * 4); \
        vreg[it] = *(const f32x4*)(vp_ + (idx_ >> 4) * D_DIM + (idx_ & 15) * 4); \
    } \
} while (0)

// ---- staging: convert + write LDS (K row-major, V transposed) ----
// NOTE: all LDS stores are short-element vectors (s16x4) — u32-typed stores
// into the short arrays caused a TBAA reorder of the wave-local P round-trip
// in R4 (absmax 3.5e29). Keep element types matching.
#define WRITE_LDS(b) do { \
    _Pragma("unroll") for (int it = 0; it < 4; ++it) { \
        const int idx_ = tid + it * 256; \
        const int row_ = idx_ >> 4, c4_ = idx_ & 15; \
        s16x4 w_; \
        _Pragma("unroll") for (int j = 0; j < 4; ++j) w_[j] = f2bf(kreg[it][j]); \
        *(s16x4*)&Kl[b][swz(row_, c4_ * 4)] = w_; \
        _Pragma("unroll") for (int j = 0; j < 4; ++j) \
            Vl[b][swz(c4_ * 4 + j, row_)] = f2bf(vreg[it][j]); \
    } \
} while (0)

// Swapped QK^T: s_[t][r] = S[kv = kv0+t*16+lg*4+r][q = qw0+lq].
// All 16 scores in a lane belong to q-row lq -> softmax = in-lane reduce + 2 shfl.
// PV output: acc[t][r] = O[q = qw0+lg*4+r][d = t*16+lq].
#define COMPUTE(qf, acc, mm, ll, qw0, kv0, b, domask) do { \
    f32x4 s_[4]; \
    _Pragma("unroll") for (int t = 0; t < 4; ++t) s_[t] = (f32x4)0.f; \
    _Pragma("unroll") for (int t = 0; t < 4; ++t) { \
        _Pragma("unroll") for (int c = 0; c < 2; ++c) { \
            bf16x8 kf_ = *(const bf16x8*)&Kl[b][swz(t * 16 + lq, c * 32 + lg * 8)]; \
            s_[t] = __builtin_amdgcn_mfma_f32_16x16x32_bf16(kf_, qf[c], s_[t], 0, 0, 0); \
        } \
    } \
    if (domask) { \
        _Pragma("unroll") for (int t = 0; t < 4; ++t) \
            _Pragma("unroll") for (int r = 0; r < 4; ++r) \
                if ((kv0) + t * 16 + lg * 4 + r > (qw0) + lq) s_[t][r] = -1e30f; \
    } \
    float pmax_ = s_[0][0]; \
    _Pragma("unroll") for (int t = 0; t < 4; ++t) \
        _Pragma("unroll") for (int r = 0; r < 4; ++r) \
            if (t | r) pmax_ = fmaxf(pmax_, s_[t][r]); \
    pmax_ = fmaxf(pmax_, __shfl_xor(pmax_, 16)); \
    pmax_ = fmaxf(pmax_, __shfl_xor(pmax_, 32)); \
    if (!__all(pmax_ <= (mm) + THR)) {           /* defer-max: rare rescale */ \
        const float mn_ = fmaxf((mm), pmax_); \
        const float f_  = EXP2((mm) - mn_); \
        (ll) *= f_; \
        _Pragma("unroll") for (int r = 0; r < 4; ++r) { \
            const float fr_ = __shfl(f_, lg * 4 + r); \
            _Pragma("unroll") for (int t = 0; t < 4; ++t) acc[t][r] *= fr_; \
        } \
        (mm) = mn_; \
    } \
    float rs_ = 0.f; \
    _Pragma("unroll") for (int t = 0; t < 4; ++t) { \
        s16x4 pw_; \
        _Pragma("unroll") for (int r = 0; r < 4; ++r) { \
            const float p_ = EXP2(s_[t][r] - (mm)); \
            rs_ += p_; \
            pw_[r] = f2bf(p_); \
        } \
        *(s16x4*)&Pl[wid][swz(lq, t * 16 + lg * 4)] = pw_; \
    } \
    rs_ += __shfl_xor(rs_, 16); \
    rs_ += __shfl_xor(rs_, 32); \
    (ll) += rs_; \
    _Pragma("unroll") for (int c = 0; c < 2; ++c) { \
        bf16x8 pf_ = *(const bf16x8*)&Pl[wid][swz(lq, c * 32 + lg * 8)]; \
        _Pragma("unroll") for (int t = 0; t < 4; ++t) { \
            bf16x8 vf_ = *(const bf16x8*)&Vl[b][swz(t * 16 + lq, c * 32 + lg * 8)]; \
            acc[t] = __builtin_amdgcn_mfma_f32_16x16x32_bf16(pf_, vf_, acc[t], 0, 0, 0); \
        } \
    } \
} while (0)

// (256,2): 2 waves/EU min -> VGPR cap 256. R3's (256,4) capped at 64 VGPRs and
// spilled ~200MB/launch to scratch (WRITE_SIZE 230MB vs 32MB output).
__global__ __launch_bounds__(256, 2)
void attn_fwd_kernel(const float* __restrict__ Q, const float* __restrict__ K,
                     const float* __restrict__ V, float* __restrict__ Out)
{
    const int bh   = blockIdx.x;          // 0..63 (fast dim -> heavy pairs first)
    const int pair = blockIdx.y;          // 0..15
    const int tid  = threadIdx.x;
    const int wid  = tid >> 6;
    const int lane = tid & 63;
    const int lq   = lane & 15;
    const int lg   = lane >> 4;

    const int qtA = NQT - 1 - pair;       // heavy q-tile (16..31)
    const int qtB = pair;                 // light q-tile (0..15)
    const int nkv = qtA + 1;

    const size_t base = (size_t)bh * S_LEN * D_DIM;
    const float* Qp = Q + base;
    const float* Kp = K + base;
    const float* Vp = V + base;
    float*       Op = Out + base;

    __shared__ __align__(16) short Kl[2][64 * 64];   // K tile [kv][d], bf16, swizzled
    __shared__ __align__(16) short Vl[2][64 * 64];   // V^T tile [d][kv], bf16, swizzled
    __shared__ __align__(16) short Pl[4][16 * 64];   // per-wave P [q][kv], bf16, swizzled

    const int qw0A = qtA * 64 + wid * 16;
    const int qw0B = qtB * 64 + wid * 16;

    // Q fragments (B-operand of swapped QK^T), pre-scaled by log2e/sqrt(D)
    bf16x8 qfA[2], qfB[2];
    {
        const float sc = 0.125f * LOG2E;
        #pragma unroll
        for (int c = 0; c < 2; ++c) {
            const float* pa = Qp + (size_t)(qw0A + lq) * D_DIM + c * 32 + lg * 8;
            const float* pb = Qp + (size_t)(qw0B + lq) * D_DIM + c * 32 + lg * 8;
            f32x4 a0 = *(const f32x4*)pa, a1 = *(const f32x4*)(pa + 4);
            f32x4 b0 = *(const f32x4*)pb, b1 = *(const f32x4*)(pb + 4);
            #pragma unroll
            for (int j = 0; j < 4; ++j) {
                qfA[c][j] = f2bf(a0[j] * sc); qfA[c][4 + j] = f2bf(a1[j] * sc);
                qfB[c][j] = f2bf(b0[j] * sc); qfB[c][4 + j] = f2bf(b1[j] * sc);
            }
        }
    }

    f32x4 accA[4], accB[4];
    #pragma unroll
    for (int t = 0; t < 4; ++t) { accA[t] = (f32x4)0.f; accB[t] = (f32x4)0.f; }
    float mA = -1e30f, lA = 0.f, mB = -1e30f, lB = 0.f;

    f32x4 kreg[4], vreg[4];

    ISSUE(0);
    WRITE_LDS(0);
    __syncthreads();

    for (int kb = 0; kb < nkv; ++kb) {
        const int  buf  = kb & 1;
        const bool more = (kb + 1) < nkv;
        if (more) ISSUE(kb + 1);                 // global loads overlap compute
        COMPUTE(qfA, accA, mA, lA, qw0A, kb * 64, buf, (kb == qtA));
        if (kb <= qtB)
            COMPUTE(qfB, accB, mB, lB, qw0B, kb * 64, buf, (kb == qtB));
        __syncthreads();                         // all reads of buf^1 done
        if (more) WRITE_LDS(buf ^ 1);
        __syncthreads();                         // next tile visible
    }

    // ---- epilogue: O[q][d] = acc / l(q) ----
    #pragma unroll
    for (int r = 0; r < 4; ++r) {
        const float lrA = __shfl(lA, lg * 4 + r);
        const float lrB = __shfl(lB, lg * 4 + r);
        const float iA = 1.f / lrA;
        const float iB = 1.f / lrB;
        #pragma unroll
        for (int t = 0; t < 4; ++t) {
            Op[(size_t)(qw0A + lg * 4 + r) * D_DIM + t * 16 + lq] = accA[t][r] * iA;
            Op[(size_t)(qw0B + lg * 4 + r) * D_DIM + t * 16 + lq] = accB[t][r] * iB;
        }
    }
}

extern "C" void kernel_launch(void* const* d_in, const int* in_sizes, int n_in,
                              void* d_out, int out_size, void* d_ws, size_t ws_size,
                              hipStream_t stream) {
    const float* q = (const float*)d_in[0];
    const float* k = (const float*)d_in[1];
    const float* v = (const float*)d_in[2];
    // d_in[3] (causal tril mask) handled analytically.
    float* out = (float*)d_out;
    (void)d_ws; (void)ws_size; (void)in_sizes; (void)n_in; (void)out_size;

    dim3 grid(4 * 16 /* B*H */, NQT / 2);
    dim3 block(256);
    attn_fwd_kernel<<<grid, block, 0, stream>>>(q, k, v, out);
}

// Round 6
// 112.251 us; speedup vs baseline: 6.6749x; 1.0767x over previous
//
#include <hip/hip_runtime.h>
#include <stdint.h>

#define S_LEN 2048
#define D_DIM 64
#define BH    64
#define NQT   32
#define LOG2E 1.44269504088896f
#define THR   8.0f

typedef __attribute__((ext_vector_type(8))) short bf16x8;
typedef __attribute__((ext_vector_type(4))) short s16x4;
typedef __attribute__((ext_vector_type(4))) float f32x4;

__device__ __forceinline__ short f2bf(float f) {
    uint32_t u = __builtin_bit_cast(uint32_t, f);
    u += 0x7FFFu + ((u >> 16) & 1u);   // RNE
    return (short)(u >> 16);
}

// XOR swizzle on short-index of a [rows][64]-short LDS tile.
// Flips short-bits 3..5 (byte bits 4..6): preserves 8B/16B alignment.
__device__ __forceinline__ int swz(int row, int col) {
    return (row * 64 + col) ^ ((row & 7) << 3);
}

#if __has_builtin(__builtin_amdgcn_exp2f)
#define EXP2(x) __builtin_amdgcn_exp2f(x)
#else
#define EXP2(x) exp2f(x)
#endif

// ============================ pre-pass kernels ============================
// ws layout (shorts): Qb [0, 8.4M) scaled bf16 [bh][s][d]
//                     Kb [8.4M, 16.8M)   bf16 [bh][s][d]
//                     Vt [16.8M, 25.2M)  bf16 [bh][d][s]  (transposed)
#define TEN_ELEMS (BH * S_LEN * D_DIM)          // 8,388,608 per tensor

__global__ __launch_bounds__(256)
void cvt_qk_kernel(const float* __restrict__ Q, const float* __restrict__ K,
                   short* __restrict__ Qb, short* __restrict__ Kb)
{
    const size_t i = (size_t)blockIdx.x * 256 + threadIdx.x;   // group of 8
    const size_t off = i * 8;
    const float sc = 0.125f * LOG2E;
    f32x4 a0 = *(const f32x4*)(Q + off), a1 = *(const f32x4*)(Q + off + 4);
    f32x4 b0 = *(const f32x4*)(K + off), b1 = *(const f32x4*)(K + off + 4);
    bf16x8 qa, kb;
    #pragma unroll
    for (int j = 0; j < 4; ++j) {
        qa[j] = f2bf(a0[j] * sc); qa[4 + j] = f2bf(a1[j] * sc);
        kb[j] = f2bf(b0[j]);      kb[4 + j] = f2bf(b1[j]);
    }
    *(bf16x8*)(Qb + off) = qa;
    *(bf16x8*)(Kb + off) = kb;
}

__global__ __launch_bounds__(256)
void vt_kernel(const float* __restrict__ V, short* __restrict__ Vt)
{
    const int kt = blockIdx.x;              // kv tile 0..31
    const int bh = blockIdx.y;
    const float* Vp = V + (size_t)bh * S_LEN * D_DIM + (size_t)kt * 64 * D_DIM;
    short* Vo = Vt + (size_t)bh * D_DIM * S_LEN;
    __shared__ short T[64][72];             // +8 pad
    const int tid = threadIdx.x;
    const int row = tid >> 2, q4 = tid & 3; // row 0..63, quarter of 64 floats
    #pragma unroll
    for (int j = 0; j < 4; ++j) {
        f32x4 v = *(const f32x4*)(Vp + row * D_DIM + q4 * 16 + j * 4);
        #pragma unroll
        for (int e = 0; e < 4; ++e) T[row][q4 * 16 + j * 4 + e] = f2bf(v[e]);
    }
    __syncthreads();
    const int d = tid >> 2, kq = tid & 3;
    #pragma unroll
    for (int j = 0; j < 4; ++j) {
        s16x4 w;
        #pragma unroll
        for (int e = 0; e < 4; ++e) w[e] = T[kq * 16 + j * 4 + e][d];
        *(s16x4*)&Vo[(size_t)d * S_LEN + kt * 64 + kq * 16 + j * 4] = w;
    }
}

// ============================ hot kernel (bf16) ============================
#define ISSUE_B(kb) do { \
    const short* kp_ = Kp + (size_t)(kb) * 64 * D_DIM; \
    const short* vp_ = Vtp + (kb) * 64; \
    _Pragma("unroll") for (int it = 0; it < 4; ++it) { \
        const int idx_ = tid + it * 256; \
        const int row_ = idx_ >> 4, c4_ = idx_ & 15; \
        kreg[it] = *(const s16x4*)(kp_ + row_ * D_DIM + c4_ * 4); \
        vreg[it] = *(const s16x4*)(vp_ + (size_t)row_ * S_LEN + c4_ * 4); \
    } \
} while (0)

#define WRITE_LDS_B(b) do { \
    _Pragma("unroll") for (int it = 0; it < 4; ++it) { \
        const int idx_ = tid + it * 256; \
        const int row_ = idx_ >> 4, c4_ = idx_ & 15; \
        *(s16x4*)&Kl[b][swz(row_, c4_ * 4)] = kreg[it]; \
        *(s16x4*)&Vl[b][swz(row_, c4_ * 4)] = vreg[it]; \
    } \
} while (0)

// Swapped QK^T: s_[t][r] = S[kv = kv0+t*16+lg*4+r][q = qw0+lq].
#define COMPUTE(qf, acc, mm, ll, qw0, kv0, b, domask) do { \
    f32x4 s_[4]; \
    _Pragma("unroll") for (int t = 0; t < 4; ++t) s_[t] = (f32x4)0.f; \
    _Pragma("unroll") for (int t = 0; t < 4; ++t) { \
        _Pragma("unroll") for (int c = 0; c < 2; ++c) { \
            bf16x8 kf_ = *(const bf16x8*)&Kl[b][swz(t * 16 + lq, c * 32 + lg * 8)]; \
            s_[t] = __builtin_amdgcn_mfma_f32_16x16x32_bf16(kf_, qf[c], s_[t], 0, 0, 0); \
        } \
    } \
    if (domask) { \
        _Pragma("unroll") for (int t = 0; t < 4; ++t) \
            _Pragma("unroll") for (int r = 0; r < 4; ++r) \
                if ((kv0) + t * 16 + lg * 4 + r > (qw0) + lq) s_[t][r] = -1e30f; \
    } \
    float pmax_ = s_[0][0]; \
    _Pragma("unroll") for (int t = 0; t < 4; ++t) \
        _Pragma("unroll") for (int r = 0; r < 4; ++r) \
            if (t | r) pmax_ = fmaxf(pmax_, s_[t][r]); \
    pmax_ = fmaxf(pmax_, __shfl_xor(pmax_, 16)); \
    pmax_ = fmaxf(pmax_, __shfl_xor(pmax_, 32)); \
    if (!__all(pmax_ <= (mm) + THR)) {           /* defer-max: rare rescale */ \
        const float mn_ = fmaxf((mm), pmax_); \
        const float f_  = EXP2((mm) - mn_); \
        (ll) *= f_; \
        _Pragma("unroll") for (int r = 0; r < 4; ++r) { \
            const float fr_ = __shfl(f_, lg * 4 + r); \
            _Pragma("unroll") for (int t = 0; t < 4; ++t) acc[t][r] *= fr_; \
        } \
        (mm) = mn_; \
    } \
    float rs_ = 0.f; \
    _Pragma("unroll") for (int t = 0; t < 4; ++t) { \
        s16x4 pw_; \
        _Pragma("unroll") for (int r = 0; r < 4; ++r) { \
            const float p_ = EXP2(s_[t][r] - (mm)); \
            rs_ += p_; \
            pw_[r] = f2bf(p_); \
        } \
        *(s16x4*)&Pl[wid][swz(lq, t * 16 + lg * 4)] = pw_; \
    } \
    rs_ += __shfl_xor(rs_, 16); \
    rs_ += __shfl_xor(rs_, 32); \
    (ll) += rs_; \
    _Pragma("unroll") for (int c = 0; c < 2; ++c) { \
        bf16x8 pf_ = *(const bf16x8*)&Pl[wid][swz(lq, c * 32 + lg * 8)]; \
        _Pragma("unroll") for (int t = 0; t < 4; ++t) { \
            bf16x8 vf_ = *(const bf16x8*)&Vl[b][swz(t * 16 + lq, c * 32 + lg * 8)]; \
            acc[t] = __builtin_amdgcn_mfma_f32_16x16x32_bf16(pf_, vf_, acc[t], 0, 0, 0); \
        } \
    } \
} while (0)

__global__ __launch_bounds__(256, 2)
void attn_fwd_bf16(const short* __restrict__ Qb, const short* __restrict__ Kb,
                   const short* __restrict__ Vt, float* __restrict__ Out)
{
    const int bh   = blockIdx.x;
    const int pair = blockIdx.y;
    const int tid  = threadIdx.x;
    const int wid  = tid >> 6;
    const int lane = tid & 63;
    const int lq   = lane & 15;
    const int lg   = lane >> 4;

    const int qtA = NQT - 1 - pair;       // heavy q-tile
    const int qtB = pair;                 // light q-tile
    const int nkv = qtA + 1;

    const short* Qp  = Qb + (size_t)bh * S_LEN * D_DIM;
    const short* Kp  = Kb + (size_t)bh * S_LEN * D_DIM;
    const short* Vtp = Vt + (size_t)bh * D_DIM * S_LEN;
    float*       Op  = Out + (size_t)bh * S_LEN * D_DIM;

    __shared__ __align__(16) short Kl[2][64 * 64];
    __shared__ __align__(16) short Vl[2][64 * 64];   // V^T tile [d][kv]
    __shared__ __align__(16) short Pl[4][16 * 64];

    const int qw0A = qtA * 64 + wid * 16;
    const int qw0B = qtB * 64 + wid * 16;

    bf16x8 qfA[2], qfB[2];
    #pragma unroll
    for (int c = 0; c < 2; ++c) {
        qfA[c] = *(const bf16x8*)(Qp + (size_t)(qw0A + lq) * D_DIM + c * 32 + lg * 8);
        qfB[c] = *(const bf16x8*)(Qp + (size_t)(qw0B + lq) * D_DIM + c * 32 + lg * 8);
    }

    f32x4 accA[4], accB[4];
    #pragma unroll
    for (int t = 0; t < 4; ++t) { accA[t] = (f32x4)0.f; accB[t] = (f32x4)0.f; }
    float mA = -1e30f, lA = 0.f, mB = -1e30f, lB = 0.f;

    s16x4 kreg[4], vreg[4];

    ISSUE_B(0);
    WRITE_LDS_B(0);
    __syncthreads();

    for (int kb = 0; kb < nkv; ++kb) {
        const int  buf  = kb & 1;
        const bool more = (kb + 1) < nkv;
        if (more) ISSUE_B(kb + 1);               // loads fly under compute
        COMPUTE(qfA, accA, mA, lA, qw0A, kb * 64, buf, (kb == qtA));
        if (kb <= qtB)
            COMPUTE(qfB, accB, mB, lB, qw0B, kb * 64, buf, (kb == qtB));
        // single barrier per tile: reads of buf^1 finished before the
        // PREVIOUS iteration's barrier, so writing buf^1 here is safe.
        if (more) {
            WRITE_LDS_B(buf ^ 1);
            __syncthreads();
        }
    }

    #pragma unroll
    for (int r = 0; r < 4; ++r) {
        const float lrA = __shfl(lA, lg * 4 + r);
        const float lrB = __shfl(lB, lg * 4 + r);
        const float iA = 1.f / lrA;
        const float iB = 1.f / lrB;
        #pragma unroll
        for (int t = 0; t < 4; ++t) {
            Op[(size_t)(qw0A + lg * 4 + r) * D_DIM + t * 16 + lq] = accA[t][r] * iA;
            Op[(size_t)(qw0B + lg * 4 + r) * D_DIM + t * 16 + lq] = accB[t][r] * iB;
        }
    }
}

// ==================== fallback (R5, fp32 staging) ====================
#define ISSUE_F(kb) do { \
    const float* kp_ = Kp + (size_t)(kb) * 64 * D_DIM; \
    const float* vp_ = Vp + (size_t)(kb) * 64 * D_DIM; \
    _Pragma("unroll") for (int it = 0; it < 4; ++it) { \
        const int idx_ = tid + it * 256; \
        fkreg[it] = *(const f32x4*)(kp_ + (idx_ >> 4) * D_DIM + (idx_ & 15) * 4); \
        fvreg[it] = *(const f32x4*)(vp_ + (idx_ >> 4) * D_DIM + (idx_ & 15) * 4); \
    } \
} while (0)

#define WRITE_LDS_F(b) do { \
    _Pragma("unroll") for (int it = 0; it < 4; ++it) { \
        const int idx_ = tid + it * 256; \
        const int row_ = idx_ >> 4, c4_ = idx_ & 15; \
        s16x4 w_; \
        _Pragma("unroll") for (int j = 0; j < 4; ++j) w_[j] = f2bf(fkreg[it][j]); \
        *(s16x4*)&Kl[b][swz(row_, c4_ * 4)] = w_; \
        _Pragma("unroll") for (int j = 0; j < 4; ++j) \
            Vl[b][swz(c4_ * 4 + j, row_)] = f2bf(fvreg[it][j]); \
    } \
} while (0)

__global__ __launch_bounds__(256, 2)
void attn_fwd_f32(const float* __restrict__ Q, const float* __restrict__ K,
                  const float* __restrict__ V, float* __restrict__ Out)
{
    const int bh   = blockIdx.x;
    const int pair = blockIdx.y;
    const int tid  = threadIdx.x;
    const int wid  = tid >> 6;
    const int lane = tid & 63;
    const int lq   = lane & 15;
    const int lg   = lane >> 4;

    const int qtA = NQT - 1 - pair;
    const int qtB = pair;
    const int nkv = qtA + 1;

    const size_t base = (size_t)bh * S_LEN * D_DIM;
    const float* Qp = Q + base;
    const float* Kp = K + base;
    const float* Vp = V + base;
    float*       Op = Out + base;

    __shared__ __align__(16) short Kl[2][64 * 64];
    __shared__ __align__(16) short Vl[2][64 * 64];
    __shared__ __align__(16) short Pl[4][16 * 64];

    const int qw0A = qtA * 64 + wid * 16;
    const int qw0B = qtB * 64 + wid * 16;

    bf16x8 qfA[2], qfB[2];
    {
        const float sc = 0.125f * LOG2E;
        #pragma unroll
        for (int c = 0; c < 2; ++c) {
            const float* pa = Qp + (size_t)(qw0A + lq) * D_DIM + c * 32 + lg * 8;
            const float* pb = Qp + (size_t)(qw0B + lq) * D_DIM + c * 32 + lg * 8;
            f32x4 a0 = *(const f32x4*)pa, a1 = *(const f32x4*)(pa + 4);
            f32x4 b0 = *(const f32x4*)pb, b1 = *(const f32x4*)(pb + 4);
            #pragma unroll
            for (int j = 0; j < 4; ++j) {
                qfA[c][j] = f2bf(a0[j] * sc); qfA[c][4 + j] = f2bf(a1[j] * sc);
                qfB[c][j] = f2bf(b0[j] * sc); qfB[c][4 + j] = f2bf(b1[j] * sc);
            }
        }
    }

    f32x4 accA[4], accB[4];
    #pragma unroll
    for (int t = 0; t < 4; ++t) { accA[t] = (f32x4)0.f; accB[t] = (f32x4)0.f; }
    float mA = -1e30f, lA = 0.f, mB = -1e30f, lB = 0.f;

    f32x4 fkreg[4], fvreg[4];

    ISSUE_F(0);
    WRITE_LDS_F(0);
    __syncthreads();

    for (int kb = 0; kb < nkv; ++kb) {
        const int  buf  = kb & 1;
        const bool more = (kb + 1) < nkv;
        if (more) ISSUE_F(kb + 1);
        COMPUTE(qfA, accA, mA, lA, qw0A, kb * 64, buf, (kb == qtA));
        if (kb <= qtB)
            COMPUTE(qfB, accB, mB, lB, qw0B, kb * 64, buf, (kb == qtB));
        __syncthreads();
        if (more) WRITE_LDS_F(buf ^ 1);
        __syncthreads();
    }

    #pragma unroll
    for (int r = 0; r < 4; ++r) {
        const float lrA = __shfl(lA, lg * 4 + r);
        const float lrB = __shfl(lB, lg * 4 + r);
        const float iA = 1.f / lrA;
        const float iB = 1.f / lrB;
        #pragma unroll
        for (int t = 0; t < 4; ++t) {
            Op[(size_t)(qw0A + lg * 4 + r) * D_DIM + t * 16 + lq] = accA[t][r] * iA;
            Op[(size_t)(qw0B + lg * 4 + r) * D_DIM + t * 16 + lq] = accB[t][r] * iB;
        }
    }
}

extern "C" void kernel_launch(void* const* d_in, const int* in_sizes, int n_in,
                              void* d_out, int out_size, void* d_ws, size_t ws_size,
                              hipStream_t stream) {
    const float* q = (const float*)d_in[0];
    const float* k = (const float*)d_in[1];
    const float* v = (const float*)d_in[2];
    float* out = (float*)d_out;
    (void)in_sizes; (void)n_in; (void)out_size;

    const size_t need = (size_t)3 * TEN_ELEMS * sizeof(short);  // 50.3 MB
    if (ws_size >= need) {
        short* Qb = (short*)d_ws;
        short* Kb = Qb + TEN_ELEMS;
        short* Vt = Kb + TEN_ELEMS;
        cvt_qk_kernel<<<TEN_ELEMS / 8 / 256, 256, 0, stream>>>(q, k, Qb, Kb);
        vt_kernel<<<dim3(S_LEN / 64, BH), 256, 0, stream>>>(v, Vt);
        attn_fwd_bf16<<<dim3(BH, NQT / 2), 256, 0, stream>>>(Qb, Kb, Vt, out);
    } else {
        attn_fwd_f32<<<dim3(BH, NQT / 2), 256, 0, stream>>>(q, k, v, out);
    }
}

// Round 9
// 97.122 us; speedup vs baseline: 7.7146x; 1.1558x over previous
//
#include <hip/hip_runtime.h>
#include <hip/hip_bf16.h>
#include <stdint.h>

#define S_LEN 2048
#define D_DIM 64
#define BH    64
#define NQT   16          // q-tiles of 128 rows
#define LOG2E 1.44269504088896f
#define THR   8.0f
#define TEN_ELEMS (BH * S_LEN * D_DIM)

typedef __attribute__((ext_vector_type(8)))  short bf16x8;
typedef __attribute__((ext_vector_type(4)))  short s16x4;
typedef __attribute__((ext_vector_type(4)))  float f32x4;
typedef __attribute__((ext_vector_type(16))) float f32x16;
typedef __attribute__((ext_vector_type(4)))  uint32_t u32x4;

__device__ __forceinline__ short f2bf(float f) {
    uint32_t u = __builtin_bit_cast(uint32_t, f);
    u += 0x7FFFu + ((u >> 16) & 1u);   // RNE
    return (short)(u >> 16);
}

// packed f32->bf16 (emits v_cvt_pk_bf16_f32); memcpy because __hip_bfloat162
// is not trivially copyable.
__device__ __forceinline__ uint32_t pkbf(float lo, float hi) {
    __hip_bfloat162 h = __float22bfloat162_rn(make_float2(lo, hi));
    uint32_t r;
    __builtin_memcpy(&r, &h, 4);
    return r;
}

// cross-half (lane ^ 32) exchange helpers — __shfl_xor has unambiguous
// semantics (R8's permlane32_swap had a direction ambiguity -> absmax 1.39).
__device__ __forceinline__ float xhalf_max(float v) {
    return fmaxf(v, __shfl_xor(v, 32));
}
__device__ __forceinline__ float xhalf_sum(float v) {
    return v + __shfl_xor(v, 32);
}

// XOR swizzle on short-index of a [rows][64]-short LDS tile (byte bits 4..6).
__device__ __forceinline__ int swz(int row, int col) {
    return (row * 64 + col) ^ ((row & 7) << 3);
}

#if __has_builtin(__builtin_amdgcn_exp2f)
#define EXP2(x) __builtin_amdgcn_exp2f(x)
#else
#define EXP2(x) exp2f(x)
#endif

// ============================ pre-pass kernels ============================
__global__ __launch_bounds__(256)
void cvt_qk_kernel(const float* __restrict__ Q, const float* __restrict__ K,
                   short* __restrict__ Qb, short* __restrict__ Kb)
{
    const size_t off = ((size_t)blockIdx.x * 256 + threadIdx.x) * 8;
    const float sc = 0.125f * LOG2E;
    f32x4 a0 = *(const f32x4*)(Q + off), a1 = *(const f32x4*)(Q + off + 4);
    f32x4 b0 = *(const f32x4*)(K + off), b1 = *(const f32x4*)(K + off + 4);
    bf16x8 qa, kb;
    #pragma unroll
    for (int j = 0; j < 4; ++j) {
        qa[j] = f2bf(a0[j] * sc); qa[4 + j] = f2bf(a1[j] * sc);
        kb[j] = f2bf(b0[j]);      kb[4 + j] = f2bf(b1[j]);
    }
    *(bf16x8*)(Qb + off) = qa;
    *(bf16x8*)(Kb + off) = kb;
}

__global__ __launch_bounds__(256)
void vt_kernel(const float* __restrict__ V, short* __restrict__ Vt)
{
    const int kt = blockIdx.x;              // kv tile 0..31
    const int bh = blockIdx.y;
    const float* Vp = V + (size_t)bh * S_LEN * D_DIM + (size_t)kt * 64 * D_DIM;
    short* Vo = Vt + (size_t)bh * D_DIM * S_LEN;
    __shared__ short T[64][72];             // +8 pad
    const int tid = threadIdx.x;
    const int row = tid >> 2, q4 = tid & 3;
    #pragma unroll
    for (int j = 0; j < 4; ++j) {
        f32x4 v = *(const f32x4*)(Vp + row * D_DIM + q4 * 16 + j * 4);
        #pragma unroll
        for (int e = 0; e < 4; ++e) T[row][q4 * 16 + j * 4 + e] = f2bf(v[e]);
    }
    __syncthreads();
    const int d = tid >> 2, kq = tid & 3;
    #pragma unroll
    for (int j = 0; j < 4; ++j) {
        s16x4 w;
        #pragma unroll
        for (int e = 0; e < 4; ++e) w[e] = T[kq * 16 + j * 4 + e][d];
        *(s16x4*)&Vo[(size_t)d * S_LEN + kt * 64 + kq * 16 + j * 4] = w;
    }
}

// ============================ hot kernel ============================
#define ISSUE_B(kb) do { \
    const short* kp_ = Kp + (size_t)(kb) * 64 * D_DIM; \
    const short* vp_ = Vtp + (kb) * 64; \
    _Pragma("unroll") for (int it = 0; it < 4; ++it) { \
        const int idx_ = tid + it * 256; \
        const int row_ = idx_ >> 4, c4_ = idx_ & 15; \
        kreg[it] = *(const s16x4*)(kp_ + row_ * D_DIM + c4_ * 4); \
        vreg[it] = *(const s16x4*)(vp_ + (size_t)row_ * S_LEN + c4_ * 4); \
    } \
} while (0)

#define WRITE_LDS_B(b) do { \
    _Pragma("unroll") for (int it = 0; it < 4; ++it) { \
        const int idx_ = tid + it * 256; \
        const int row_ = idx_ >> 4, c4_ = idx_ & 15; \
        *(s16x4*)&Kl[b][swz(row_, c4_ * 4)] = kreg[it]; \
        *(s16x4*)&Vl[b][swz(row_, c4_ * 4)] = vreg[it]; \
    } \
} while (0)

// Build one PV A-fragment (8 bf16 = kv slice + hi*8 + 0..7) from the lane's
// 8 f32 P-values (kv = (r&3)+8*(r>>2)+4*hi).  Direction-safe: partner words
// fetched with __shfl_xor(.,32), then per-half select.
//   hi=0 needs [x,y, partner_x, partner_y] = kv 0..7   (+slice)
//   hi=1 needs [partner_u, partner_v, u,v] = kv 8..15  (+slice)
#define MKFRAG(dst, sv, R0) do { \
    uint32_t x_ = pkbf(sv[(R0)+0], sv[(R0)+1]), y_ = pkbf(sv[(R0)+2], sv[(R0)+3]); \
    uint32_t u_ = pkbf(sv[(R0)+4], sv[(R0)+5]), v_ = pkbf(sv[(R0)+6], sv[(R0)+7]); \
    const uint32_t px_ = (uint32_t)__shfl_xor((int)x_, 32); \
    const uint32_t py_ = (uint32_t)__shfl_xor((int)y_, 32); \
    const uint32_t pu_ = (uint32_t)__shfl_xor((int)u_, 32); \
    const uint32_t pv_ = (uint32_t)__shfl_xor((int)v_, 32); \
    u32x4 t_; \
    t_[0] = hi ? pu_ : x_;  t_[1] = hi ? pv_ : y_; \
    t_[2] = hi ? u_  : px_; t_[3] = hi ? v_  : py_; \
    dst = __builtin_bit_cast(bf16x8, t_); \
} while (0)

#define PVSTEP(pa, koff, acc0, acc1, b) do { \
    bf16x8 vf0_ = *(const bf16x8*)&Vl[b][swz(lq32,      (koff) + hi * 8)]; \
    bf16x8 vf1_ = *(const bf16x8*)&Vl[b][swz(32 + lq32, (koff) + hi * 8)]; \
    acc0 = __builtin_amdgcn_mfma_f32_32x32x16_bf16(pa, vf0_, acc0, 0, 0, 0); \
    acc1 = __builtin_amdgcn_mfma_f32_32x32x16_bf16(pa, vf1_, acc1, 0, 0, 0); \
} while (0)

// Swapped QK^T with 32x32x16: S^T[kv][q]; lane: q = lq32,
// kv = kvsub*32 + (r&3) + 8*(r>>2) + 4*hi.  Softmax fully in-lane + 1 xhalf.
#define COMPUTE32(qf, acc0, acc1, mm, ll, q0, kv0, b) do { \
    f32x16 s0_ = (f32x16)0.f, s1_ = (f32x16)0.f; \
    _Pragma("unroll") for (int c = 0; c < 4; ++c) { \
        bf16x8 k0_ = *(const bf16x8*)&Kl[b][swz(lq32,      c * 16 + hi * 8)]; \
        bf16x8 k1_ = *(const bf16x8*)&Kl[b][swz(32 + lq32, c * 16 + hi * 8)]; \
        s0_ = __builtin_amdgcn_mfma_f32_32x32x16_bf16(k0_, qf[c], s0_, 0, 0, 0); \
        s1_ = __builtin_amdgcn_mfma_f32_32x32x16_bf16(k1_, qf[c], s1_, 0, 0, 0); \
    } \
    if ((kv0) + 63 > (q0)) {   /* diagonal tile: causal mask */ \
        _Pragma("unroll") for (int r = 0; r < 16; ++r) { \
            const int kvr_ = (r & 3) + 8 * (r >> 2) + 4 * hi; \
            if ((kv0) + kvr_      > (q0) + lq32) s0_[r] = -1e30f; \
            if ((kv0) + 32 + kvr_ > (q0) + lq32) s1_[r] = -1e30f; \
        } \
    } \
    float m0_ = fmaxf(s0_[0], s1_[0]), m1_ = fmaxf(s0_[1], s1_[1]); \
    float m2_ = fmaxf(s0_[2], s1_[2]), m3_ = fmaxf(s0_[3], s1_[3]); \
    _Pragma("unroll") for (int r = 4; r < 16; r += 4) { \
        m0_ = fmaxf(m0_, fmaxf(s0_[r],     s1_[r])); \
        m1_ = fmaxf(m1_, fmaxf(s0_[r + 1], s1_[r + 1])); \
        m2_ = fmaxf(m2_, fmaxf(s0_[r + 2], s1_[r + 2])); \
        m3_ = fmaxf(m3_, fmaxf(s0_[r + 3], s1_[r + 3])); \
    } \
    float pmax_ = xhalf_max(fmaxf(fmaxf(m0_, m1_), fmaxf(m2_, m3_))); \
    if (!__all(pmax_ <= (mm) + THR)) {      /* defer-max: rare rescale */ \
        const float mn_ = fmaxf((mm), pmax_); \
        const float f_  = EXP2((mm) - mn_); \
        (ll) *= f_; \
        _Pragma("unroll") for (int r = 0; r < 16; ++r) { \
            const float fr_ = __shfl(f_, (r & 3) + 8 * (r >> 2) + 4 * hi); \
            acc0[r] *= fr_; acc1[r] *= fr_; \
        } \
        (mm) = mn_; \
    } \
    float t0_ = 0.f, t1_ = 0.f, t2_ = 0.f, t3_ = 0.f; \
    _Pragma("unroll") for (int r = 0; r < 16; r += 4) { \
        s0_[r]     = EXP2(s0_[r]     - (mm)); s1_[r]     = EXP2(s1_[r]     - (mm)); \
        s0_[r + 1] = EXP2(s0_[r + 1] - (mm)); s1_[r + 1] = EXP2(s1_[r + 1] - (mm)); \
        s0_[r + 2] = EXP2(s0_[r + 2] - (mm)); s1_[r + 2] = EXP2(s1_[r + 2] - (mm)); \
        s0_[r + 3] = EXP2(s0_[r + 3] - (mm)); s1_[r + 3] = EXP2(s1_[r + 3] - (mm)); \
        t0_ += s0_[r]     + s1_[r]; \
        t1_ += s0_[r + 1] + s1_[r + 1]; \
        t2_ += s0_[r + 2] + s1_[r + 2]; \
        t3_ += s0_[r + 3] + s1_[r + 3]; \
    } \
    (ll) += (t0_ + t1_) + (t2_ + t3_);      /* in-lane half-sum; combine at end */ \
    bf16x8 pa0_, pa1_, pa2_, pa3_; \
    MKFRAG(pa0_, s0_, 0); MKFRAG(pa1_, s0_, 8); \
    MKFRAG(pa2_, s1_, 0); MKFRAG(pa3_, s1_, 8); \
    PVSTEP(pa0_, 0,  acc0, acc1, b); \
    PVSTEP(pa1_, 16, acc0, acc1, b); \
    PVSTEP(pa2_, 32, acc0, acc1, b); \
    PVSTEP(pa3_, 48, acc0, acc1, b); \
} while (0)

__global__ __launch_bounds__(256, 2)
void attn_fwd_bf16(const short* __restrict__ Qb, const short* __restrict__ Kb,
                   const short* __restrict__ Vt, float* __restrict__ Out)
{
    const int bh   = blockIdx.x;          // 0..63
    const int pair = blockIdx.y;          // 0..7
    const int tid  = threadIdx.x;
    const int wid  = tid >> 6;
    const int lane = tid & 63;
    const int lq32 = lane & 31;
    const int hi   = lane >> 5;

    const int qtA = NQT - 1 - pair;       // heavy 128-row q-tile (8..15)
    const int qtB = pair;                 // light q-tile (0..7)
    const int nkv = 2 * qtA + 2;          // 64-wide kv tiles

    const short* Qp  = Qb + (size_t)bh * S_LEN * D_DIM;
    const short* Kp  = Kb + (size_t)bh * S_LEN * D_DIM;
    const short* Vtp = Vt + (size_t)bh * D_DIM * S_LEN;
    float*       Op  = Out + (size_t)bh * S_LEN * D_DIM;

    __shared__ __align__(16) short Kl[2][64 * 64];
    __shared__ __align__(16) short Vl[2][64 * 64];   // V^T tile [d][kv]

    const int q0A = qtA * 128 + wid * 32;
    const int q0B = qtB * 128 + wid * 32;

    // Q fragments (B-operand): col q = lq32, k(d) = c*16 + hi*8 + j
    bf16x8 qfA[4], qfB[4];
    #pragma unroll
    for (int c = 0; c < 4; ++c) {
        qfA[c] = *(const bf16x8*)(Qp + (size_t)(q0A + lq32) * D_DIM + c * 16 + hi * 8);
        qfB[c] = *(const bf16x8*)(Qp + (size_t)(q0B + lq32) * D_DIM + c * 16 + hi * 8);
    }

    f32x16 accA0 = (f32x16)0.f, accA1 = (f32x16)0.f;
    f32x16 accB0 = (f32x16)0.f, accB1 = (f32x16)0.f;
    float mA = -1e30f, lA = 0.f, mB = -1e30f, lB = 0.f;

    s16x4 kreg[4], vreg[4];

    ISSUE_B(0);
    WRITE_LDS_B(0);
    __syncthreads();

    for (int j = 0; j < nkv; ++j) {
        const int  kv0  = j * 64;
        const int  buf  = j & 1;
        const bool more = (j + 1) < nkv;
        if (more) ISSUE_B(j + 1);                     // loads fly under compute
        if (kv0 <= q0A + 31) COMPUTE32(qfA, accA0, accA1, mA, lA, q0A, kv0, buf);
        if (kv0 <= q0B + 31) COMPUTE32(qfB, accB0, accB1, mB, lB, q0B, kv0, buf);
        if (more) {                                   // single barrier per tile
            WRITE_LDS_B(buf ^ 1);
            __syncthreads();
        }
    }

    // ---- epilogue: combine half-sums, O = acc / l ----
    lA = xhalf_sum(lA);
    lB = xhalf_sum(lB);
    const float iA = 1.f / lA;
    const float iB = 1.f / lB;
    #pragma unroll
    for (int r = 0; r < 16; ++r) {
        const int qr   = (r & 3) + 8 * (r >> 2) + 4 * hi;
        const float vA = __shfl(iA, qr);
        const float vB = __shfl(iB, qr);
        Op[(size_t)(q0A + qr) * D_DIM + lq32]      = accA0[r] * vA;
        Op[(size_t)(q0A + qr) * D_DIM + 32 + lq32] = accA1[r] * vA;
        Op[(size_t)(q0B + qr) * D_DIM + lq32]      = accB0[r] * vB;
        Op[(size_t)(q0B + qr) * D_DIM + 32 + lq32] = accB1[r] * vB;
    }
}

extern "C" void kernel_launch(void* const* d_in, const int* in_sizes, int n_in,
                              void* d_out, int out_size, void* d_ws, size_t ws_size,
                              hipStream_t stream) {
    const float* q = (const float*)d_in[0];
    const float* k = (const float*)d_in[1];
    const float* v = (const float*)d_in[2];
    // d_in[3] (causal tril mask) handled analytically.
    float* out = (float*)d_out;
    (void)in_sizes; (void)n_in; (void)out_size; (void)ws_size;

    // ws: Qb, Kb, Vt bf16 tensors (50.3 MB; harness ws verified >= this in R6)
    short* Qb = (short*)d_ws;
    short* Kb = Qb + TEN_ELEMS;
    short* Vt = Kb + TEN_ELEMS;
    cvt_qk_kernel<<<TEN_ELEMS / 8 / 256, 256, 0, stream>>>(q, k, Qb, Kb);
    vt_kernel<<<dim3(S_LEN / 64, BH), 256, 0, stream>>>(v, Vt);
    attn_fwd_bf16<<<dim3(BH, NQT / 2), 256, 0, stream>>>(Qb, Kb, Vt, out);
}

// Round 10
// 91.082 us; speedup vs baseline: 8.2263x; 1.0663x over previous
//
#include <hip/hip_runtime.h>
#include <hip/hip_bf16.h>
#include <stdint.h>

#define S_LEN 2048
#define D_DIM 64
#define BH    64
#define NQT   16          // q-tiles of 128 rows
#define LOG2E 1.44269504088896f
#define THR   8.0f
#define TEN_ELEMS (BH * S_LEN * D_DIM)

typedef __attribute__((ext_vector_type(8)))  short bf16x8;
typedef __attribute__((ext_vector_type(4)))  short s16x4;
typedef __attribute__((ext_vector_type(4)))  float f32x4;
typedef __attribute__((ext_vector_type(16))) float f32x16;
typedef __attribute__((ext_vector_type(4)))  uint32_t u32x4;

__device__ __forceinline__ short f2bf(float f) {
    uint32_t u = __builtin_bit_cast(uint32_t, f);
    u += 0x7FFFu + ((u >> 16) & 1u);   // RNE
    return (short)(u >> 16);
}

// packed f32->bf16 (emits v_cvt_pk_bf16_f32); memcpy because __hip_bfloat162
// is not trivially copyable.
__device__ __forceinline__ uint32_t pkbf(float lo, float hi) {
    __hip_bfloat162 h = __float22bfloat162_rn(make_float2(lo, hi));
    uint32_t r;
    __builtin_memcpy(&r, &h, 4);
    return r;
}

// cross-half (lane ^ 32) exchange helpers — unambiguous semantics.
__device__ __forceinline__ float xhalf_max(float v) {
    return fmaxf(v, __shfl_xor(v, 32));
}
__device__ __forceinline__ float xhalf_sum(float v) {
    return v + __shfl_xor(v, 32);
}

// XOR swizzle on short-index of a [rows][64]-short LDS tile (byte bits 4..6).
__device__ __forceinline__ int swz(int row, int col) {
    return (row * 64 + col) ^ ((row & 7) << 3);
}

#if __has_builtin(__builtin_amdgcn_exp2f)
#define EXP2(x) __builtin_amdgcn_exp2f(x)
#else
#define EXP2(x) exp2f(x)
#endif

// ============================ pre-pass kernels ============================
__global__ __launch_bounds__(256)
void cvt_qk_kernel(const float* __restrict__ Q, const float* __restrict__ K,
                   short* __restrict__ Qb, short* __restrict__ Kb)
{
    const size_t off = ((size_t)blockIdx.x * 256 + threadIdx.x) * 8;
    const float sc = 0.125f * LOG2E;
    f32x4 a0 = *(const f32x4*)(Q + off), a1 = *(const f32x4*)(Q + off + 4);
    f32x4 b0 = *(const f32x4*)(K + off), b1 = *(const f32x4*)(K + off + 4);
    bf16x8 qa, kb;
    #pragma unroll
    for (int j = 0; j < 4; ++j) {
        qa[j] = f2bf(a0[j] * sc); qa[4 + j] = f2bf(a1[j] * sc);
        kb[j] = f2bf(b0[j]);      kb[4 + j] = f2bf(b1[j]);
    }
    *(bf16x8*)(Qb + off) = qa;
    *(bf16x8*)(Kb + off) = kb;
}

__global__ __launch_bounds__(256)
void vt_kernel(const float* __restrict__ V, short* __restrict__ Vt)
{
    const int kt = blockIdx.x;              // kv tile 0..31
    const int bh = blockIdx.y;
    const float* Vp = V + (size_t)bh * S_LEN * D_DIM + (size_t)kt * 64 * D_DIM;
    short* Vo = Vt + (size_t)bh * D_DIM * S_LEN;
    __shared__ short T[64][72];             // +8 pad
    const int tid = threadIdx.x;
    const int row = tid >> 2, q4 = tid & 3;
    #pragma unroll
    for (int j = 0; j < 4; ++j) {
        f32x4 v = *(const f32x4*)(Vp + row * D_DIM + q4 * 16 + j * 4);
        #pragma unroll
        for (int e = 0; e < 4; ++e) T[row][q4 * 16 + j * 4 + e] = f2bf(v[e]);
    }
    __syncthreads();
    const int d = tid >> 2, kq = tid & 3;
    #pragma unroll
    for (int j = 0; j < 4; ++j) {
        s16x4 w;
        #pragma unroll
        for (int e = 0; e < 4; ++e) w[e] = T[kq * 16 + j * 4 + e][d];
        *(s16x4*)&Vo[(size_t)d * S_LEN + kt * 64 + kq * 16 + j * 4] = w;
    }
}

// ============================ hot kernel ============================
#define ISSUE_B(kb) do { \
    const short* kp_ = Kp + (size_t)(kb) * 64 * D_DIM; \
    const short* vp_ = Vtp + (kb) * 64; \
    _Pragma("unroll") for (int it = 0; it < 4; ++it) { \
        const int idx_ = tid + it * 256; \
        const int row_ = idx_ >> 4, c4_ = idx_ & 15; \
        kreg[it] = *(const s16x4*)(kp_ + row_ * D_DIM + c4_ * 4); \
        vreg[it] = *(const s16x4*)(vp_ + (size_t)row_ * S_LEN + c4_ * 4); \
    } \
} while (0)

#define WRITE_LDS_B(b) do { \
    _Pragma("unroll") for (int it = 0; it < 4; ++it) { \
        const int idx_ = tid + it * 256; \
        const int row_ = idx_ >> 4, c4_ = idx_ & 15; \
        *(s16x4*)&Kl[b][swz(row_, c4_ * 4)] = kreg[it]; \
        *(s16x4*)&Vl[b][swz(row_, c4_ * 4)] = vreg[it]; \
    } \
} while (0)

// Build one PV A-fragment (8 bf16 = kv slice + hi*8 + 0..7) from the lane's
// 8 f32 P-values (kv = (r&3)+8*(r>>2)+4*hi).  Direction-safe cross-half
// exchange via __shfl_xor(.,32) + per-half select (validated R9).
#define MKFRAG(dst, sv, R0) do { \
    uint32_t x_ = pkbf(sv[(R0)+0], sv[(R0)+1]), y_ = pkbf(sv[(R0)+2], sv[(R0)+3]); \
    uint32_t u_ = pkbf(sv[(R0)+4], sv[(R0)+5]), v_ = pkbf(sv[(R0)+6], sv[(R0)+7]); \
    const uint32_t px_ = (uint32_t)__shfl_xor((int)x_, 32); \
    const uint32_t py_ = (uint32_t)__shfl_xor((int)y_, 32); \
    const uint32_t pu_ = (uint32_t)__shfl_xor((int)u_, 32); \
    const uint32_t pv_ = (uint32_t)__shfl_xor((int)v_, 32); \
    u32x4 t_; \
    t_[0] = hi ? pu_ : x_;  t_[1] = hi ? pv_ : y_; \
    t_[2] = hi ? u_  : px_; t_[3] = hi ? v_  : py_; \
    dst = __builtin_bit_cast(bf16x8, t_); \
} while (0)

#define PVSTEP(pa, koff, acc0, acc1, b) do { \
    bf16x8 vf0_ = *(const bf16x8*)&Vl[b][swz(lq32,      (koff) + hi * 8)]; \
    bf16x8 vf1_ = *(const bf16x8*)&Vl[b][swz(32 + lq32, (koff) + hi * 8)]; \
    acc0 = __builtin_amdgcn_mfma_f32_32x32x16_bf16(pa, vf0_, acc0, 0, 0, 0); \
    acc1 = __builtin_amdgcn_mfma_f32_32x32x16_bf16(pa, vf1_, acc1, 0, 0, 0); \
} while (0)

// Swapped QK^T with 32x32x16: S^T[kv][q]; lane: q = lq32,
// kv = kvsub*32 + (r&3) + 8*(r>>2) + 4*hi.  Softmax fully in-lane + 1 xhalf.
// s_setprio(1) wraps the two MFMA clusters (T5; +4-7% attn, m191).
#define COMPUTE32(qf, acc0, acc1, mm, ll, q0, kv0, b) do { \
    f32x16 s0_ = (f32x16)0.f, s1_ = (f32x16)0.f; \
    __builtin_amdgcn_s_setprio(1); \
    _Pragma("unroll") for (int c = 0; c < 4; ++c) { \
        bf16x8 k0_ = *(const bf16x8*)&Kl[b][swz(lq32,      c * 16 + hi * 8)]; \
        bf16x8 k1_ = *(const bf16x8*)&Kl[b][swz(32 + lq32, c * 16 + hi * 8)]; \
        s0_ = __builtin_amdgcn_mfma_f32_32x32x16_bf16(k0_, qf[c], s0_, 0, 0, 0); \
        s1_ = __builtin_amdgcn_mfma_f32_32x32x16_bf16(k1_, qf[c], s1_, 0, 0, 0); \
    } \
    __builtin_amdgcn_s_setprio(0); \
    if ((kv0) + 63 > (q0)) {   /* diagonal tile: causal mask */ \
        _Pragma("unroll") for (int r = 0; r < 16; ++r) { \
            const int kvr_ = (r & 3) + 8 * (r >> 2) + 4 * hi; \
            if ((kv0) + kvr_      > (q0) + lq32) s0_[r] = -1e30f; \
            if ((kv0) + 32 + kvr_ > (q0) + lq32) s1_[r] = -1e30f; \
        } \
    } \
    float m0_ = fmaxf(s0_[0], s1_[0]), m1_ = fmaxf(s0_[1], s1_[1]); \
    float m2_ = fmaxf(s0_[2], s1_[2]), m3_ = fmaxf(s0_[3], s1_[3]); \
    _Pragma("unroll") for (int r = 4; r < 16; r += 4) { \
        m0_ = fmaxf(m0_, fmaxf(s0_[r],     s1_[r])); \
        m1_ = fmaxf(m1_, fmaxf(s0_[r + 1], s1_[r + 1])); \
        m2_ = fmaxf(m2_, fmaxf(s0_[r + 2], s1_[r + 2])); \
        m3_ = fmaxf(m3_, fmaxf(s0_[r + 3], s1_[r + 3])); \
    } \
    float pmax_ = xhalf_max(fmaxf(fmaxf(m0_, m1_), fmaxf(m2_, m3_))); \
    if (!__all(pmax_ <= (mm) + THR)) {      /* defer-max: rare rescale */ \
        const float mn_ = fmaxf((mm), pmax_); \
        const float f_  = EXP2((mm) - mn_); \
        (ll) *= f_; \
        _Pragma("unroll") for (int r = 0; r < 16; ++r) { \
            const float fr_ = __shfl(f_, (r & 3) + 8 * (r >> 2) + 4 * hi); \
            acc0[r] *= fr_; acc1[r] *= fr_; \
        } \
        (mm) = mn_; \
    } \
    float t0_ = 0.f, t1_ = 0.f, t2_ = 0.f, t3_ = 0.f; \
    _Pragma("unroll") for (int r = 0; r < 16; r += 4) { \
        s0_[r]     = EXP2(s0_[r]     - (mm)); s1_[r]     = EXP2(s1_[r]     - (mm)); \
        s0_[r + 1] = EXP2(s0_[r + 1] - (mm)); s1_[r + 1] = EXP2(s1_[r + 1] - (mm)); \
        s0_[r + 2] = EXP2(s0_[r + 2] - (mm)); s1_[r + 2] = EXP2(s1_[r + 2] - (mm)); \
        s0_[r + 3] = EXP2(s0_[r + 3] - (mm)); s1_[r + 3] = EXP2(s1_[r + 3] - (mm)); \
        t0_ += s0_[r]     + s1_[r]; \
        t1_ += s0_[r + 1] + s1_[r + 1]; \
        t2_ += s0_[r + 2] + s1_[r + 2]; \
        t3_ += s0_[r + 3] + s1_[r + 3]; \
    } \
    (ll) += (t0_ + t1_) + (t2_ + t3_);      /* in-lane half-sum; combine at end */ \
    bf16x8 pa0_, pa1_, pa2_, pa3_; \
    MKFRAG(pa0_, s0_, 0); MKFRAG(pa1_, s0_, 8); \
    MKFRAG(pa2_, s1_, 0); MKFRAG(pa3_, s1_, 8); \
    __builtin_amdgcn_s_setprio(1); \
    PVSTEP(pa0_, 0,  acc0, acc1, b); \
    PVSTEP(pa1_, 16, acc0, acc1, b); \
    PVSTEP(pa2_, 32, acc0, acc1, b); \
    PVSTEP(pa3_, 48, acc0, acc1, b); \
    __builtin_amdgcn_s_setprio(0); \
} while (0)

// Un-paired: one 128-row q-tile per block, grid 64x16 = 1024 blocks ->
// up to 4 blocks/CU (VGPR<=128, LDS 32KB x4 = 128KB). R9's pairing capped
// the grid at 512 = 2 blocks/CU (19.5% occupancy, stall-bound).
__global__ __launch_bounds__(256, 2)
void attn_fwd_bf16(const short* __restrict__ Qb, const short* __restrict__ Kb,
                   const short* __restrict__ Vt, float* __restrict__ Out)
{
    const int bh   = blockIdx.x;          // 0..63 (fast dim)
    const int qt   = NQT - 1 - blockIdx.y; // heavy q-tiles dispatch first
    const int tid  = threadIdx.x;
    const int wid  = tid >> 6;
    const int lane = tid & 63;
    const int lq32 = lane & 31;
    const int hi   = lane >> 5;

    const int nkv = 2 * qt + 2;           // 64-wide kv tiles

    const short* Qp  = Qb + (size_t)bh * S_LEN * D_DIM;
    const short* Kp  = Kb + (size_t)bh * S_LEN * D_DIM;
    const short* Vtp = Vt + (size_t)bh * D_DIM * S_LEN;
    float*       Op  = Out + (size_t)bh * S_LEN * D_DIM;

    __shared__ __align__(16) short Kl[2][64 * 64];
    __shared__ __align__(16) short Vl[2][64 * 64];   // V^T tile [d][kv]

    const int q0 = qt * 128 + wid * 32;

    // Q fragments (B-operand): col q = lq32, k(d) = c*16 + hi*8 + j
    bf16x8 qf[4];
    #pragma unroll
    for (int c = 0; c < 4; ++c)
        qf[c] = *(const bf16x8*)(Qp + (size_t)(q0 + lq32) * D_DIM + c * 16 + hi * 8);

    f32x16 acc0 = (f32x16)0.f, acc1 = (f32x16)0.f;
    float m = -1e30f, l = 0.f;

    s16x4 kreg[4], vreg[4];

    ISSUE_B(0);
    WRITE_LDS_B(0);
    __syncthreads();

    for (int j = 0; j < nkv; ++j) {
        const int  kv0  = j * 64;
        const int  buf  = j & 1;
        const bool more = (j + 1) < nkv;
        if (more) ISSUE_B(j + 1);                     // loads fly under compute
        if (kv0 <= q0 + 31) COMPUTE32(qf, acc0, acc1, m, l, q0, kv0, buf);
        if (more) {                                   // single barrier per tile
            WRITE_LDS_B(buf ^ 1);
            __syncthreads();
        }
    }

    // ---- epilogue: combine half-sums, O = acc / l ----
    l = xhalf_sum(l);
    const float il = 1.f / l;
    #pragma unroll
    for (int r = 0; r < 16; ++r) {
        const int qr   = (r & 3) + 8 * (r >> 2) + 4 * hi;
        const float vl = __shfl(il, qr);
        Op[(size_t)(q0 + qr) * D_DIM + lq32]      = acc0[r] * vl;
        Op[(size_t)(q0 + qr) * D_DIM + 32 + lq32] = acc1[r] * vl;
    }
}

extern "C" void kernel_launch(void* const* d_in, const int* in_sizes, int n_in,
                              void* d_out, int out_size, void* d_ws, size_t ws_size,
                              hipStream_t stream) {
    const float* q = (const float*)d_in[0];
    const float* k = (const float*)d_in[1];
    const float* v = (const float*)d_in[2];
    // d_in[3] (causal tril mask) handled analytically.
    float* out = (float*)d_out;
    (void)in_sizes; (void)n_in; (void)out_size; (void)ws_size;

    // ws: Qb, Kb, Vt bf16 tensors (50.3 MB; harness ws verified >= this in R6)
    short* Qb = (short*)d_ws;
    short* Kb = Qb + TEN_ELEMS;
    short* Vt = Kb + TEN_ELEMS;
    cvt_qk_kernel<<<TEN_ELEMS / 8 / 256, 256, 0, stream>>>(q, k, Qb, Kb);
    vt_kernel<<<dim3(S_LEN / 64, BH), 256, 0, stream>>>(v, Vt);
    attn_fwd_bf16<<<dim3(BH, NQT), 256, 0, stream>>>(Qb, Kb, Vt, out);
}

// Round 11
// 87.036 us; speedup vs baseline: 8.6087x; 1.0465x over previous
//
#include <hip/hip_runtime.h>
#include <hip/hip_bf16.h>
#include <stdint.h>

#define S_LEN 2048
#define D_DIM 64
#define BH    64
#define NQT   16          // q-tiles of 128 rows
#define LOG2E 1.44269504088896f
#define THR   8.0f
#define TEN_ELEMS (BH * S_LEN * D_DIM)

typedef __attribute__((ext_vector_type(8)))  short bf16x8;
typedef __attribute__((ext_vector_type(4)))  short s16x4;
typedef __attribute__((ext_vector_type(4)))  float f32x4;
typedef __attribute__((ext_vector_type(16))) float f32x16;
typedef __attribute__((ext_vector_type(4)))  uint32_t u32x4;

__device__ __forceinline__ short f2bf(float f) {
    uint32_t u = __builtin_bit_cast(uint32_t, f);
    u += 0x7FFFu + ((u >> 16) & 1u);   // RNE
    return (short)(u >> 16);
}

// packed f32->bf16 (emits v_cvt_pk_bf16_f32); memcpy because __hip_bfloat162
// is not trivially copyable.
__device__ __forceinline__ uint32_t pkbf(float lo, float hi) {
    __hip_bfloat162 h = __float22bfloat162_rn(make_float2(lo, hi));
    uint32_t r;
    __builtin_memcpy(&r, &h, 4);
    return r;
}

// cross-half (lane ^ 32) exchange helpers — unambiguous semantics.
__device__ __forceinline__ float xhalf_max(float v) {
    return fmaxf(v, __shfl_xor(v, 32));
}
__device__ __forceinline__ float xhalf_sum(float v) {
    return v + __shfl_xor(v, 32);
}

// XOR swizzle on short-index of a [rows][64]-short LDS tile (byte bits 4..6).
__device__ __forceinline__ int swz(int row, int col) {
    return (row * 64 + col) ^ ((row & 7) << 3);
}

#if __has_builtin(__builtin_amdgcn_exp2f)
#define EXP2(x) __builtin_amdgcn_exp2f(x)
#else
#define EXP2(x) exp2f(x)
#endif

// ============================ pre-pass kernels ============================
__global__ __launch_bounds__(256)
void cvt_qk_kernel(const float* __restrict__ Q, const float* __restrict__ K,
                   short* __restrict__ Qb, short* __restrict__ Kb)
{
    const size_t off = ((size_t)blockIdx.x * 256 + threadIdx.x) * 8;
    const float sc = 0.125f * LOG2E;
    f32x4 a0 = *(const f32x4*)(Q + off), a1 = *(const f32x4*)(Q + off + 4);
    f32x4 b0 = *(const f32x4*)(K + off), b1 = *(const f32x4*)(K + off + 4);
    bf16x8 qa, kb;
    #pragma unroll
    for (int j = 0; j < 4; ++j) {
        qa[j] = f2bf(a0[j] * sc); qa[4 + j] = f2bf(a1[j] * sc);
        kb[j] = f2bf(b0[j]);      kb[4 + j] = f2bf(b1[j]);
    }
    *(bf16x8*)(Qb + off) = qa;
    *(bf16x8*)(Kb + off) = kb;
}

// V^T pre-pass with kv quad-permute: within every 16-row kv group, V rows
// {4..7} are stored at positions {8..11} and vice versa.  This makes the
// stored kv order match the MFMA D->A slot order sigma(hi,j) =
// (j&3)+8*(j>>2)+4*hi, so the PV A-fragment is a straight pack of each
// lane's own P values — NO cross-lane exchange in the hot loop.
__global__ __launch_bounds__(256)
void vt_kernel(const float* __restrict__ V, short* __restrict__ Vt)
{
    const int kt = blockIdx.x;              // kv tile 0..31
    const int bh = blockIdx.y;
    const float* Vp = V + (size_t)bh * S_LEN * D_DIM + (size_t)kt * 64 * D_DIM;
    short* Vo = Vt + (size_t)bh * D_DIM * S_LEN;
    __shared__ short T[64][72];             // +8 pad
    const int tid = threadIdx.x;
    const int row = tid >> 2, q4 = tid & 3;
    #pragma unroll
    for (int j = 0; j < 4; ++j) {
        f32x4 v = *(const f32x4*)(Vp + row * D_DIM + q4 * 16 + j * 4);
        #pragma unroll
        for (int e = 0; e < 4; ++e) T[row][q4 * 16 + j * 4 + e] = f2bf(v[e]);
    }
    __syncthreads();
    const int d = tid >> 2, kq = tid & 3;
    #pragma unroll
    for (int j = 0; j < 4; ++j) {
        s16x4 w;
        #pragma unroll
        for (int e = 0; e < 4; ++e) w[e] = T[kq * 16 + j * 4 + e][d];
        const int jd = (j == 1) ? 2 : ((j == 2) ? 1 : j);   // quad 1 <-> 2
        *(s16x4*)&Vo[(size_t)d * S_LEN + kt * 64 + kq * 16 + jd * 4] = w;
    }
}

// ============================ hot kernel ============================
#define ISSUE_B(kb) do { \
    const short* kp_ = Kp + (size_t)(kb) * 64 * D_DIM; \
    const short* vp_ = Vtp + (kb) * 64; \
    _Pragma("unroll") for (int it = 0; it < 4; ++it) { \
        const int idx_ = tid + it * 256; \
        const int row_ = idx_ >> 4, c4_ = idx_ & 15; \
        kreg[it] = *(const s16x4*)(kp_ + row_ * D_DIM + c4_ * 4); \
        vreg[it] = *(const s16x4*)(vp_ + (size_t)row_ * S_LEN + c4_ * 4); \
    } \
} while (0)

#define WRITE_LDS_B(b) do { \
    _Pragma("unroll") for (int it = 0; it < 4; ++it) { \
        const int idx_ = tid + it * 256; \
        const int row_ = idx_ >> 4, c4_ = idx_ & 15; \
        *(s16x4*)&Kl[b][swz(row_, c4_ * 4)] = kreg[it]; \
        *(s16x4*)&Vl[b][swz(row_, c4_ * 4)] = vreg[it]; \
    } \
} while (0)

// PV A-fragment: straight pack of the lane's 8 P-values (V rows were
// pre-permuted by sigma in vt_kernel, so slot order already matches).
#define MKFRAG(dst, sv, R0) do { \
    u32x4 t_; \
    t_[0] = pkbf(sv[(R0)+0], sv[(R0)+1]); \
    t_[1] = pkbf(sv[(R0)+2], sv[(R0)+3]); \
    t_[2] = pkbf(sv[(R0)+4], sv[(R0)+5]); \
    t_[3] = pkbf(sv[(R0)+6], sv[(R0)+7]); \
    dst = __builtin_bit_cast(bf16x8, t_); \
} while (0)

#define PVSTEP(pa, koff, acc0, acc1, b) do { \
    bf16x8 vf0_ = *(const bf16x8*)&Vl[b][swz(lq32,      (koff) + hi * 8)]; \
    bf16x8 vf1_ = *(const bf16x8*)&Vl[b][swz(32 + lq32, (koff) + hi * 8)]; \
    acc0 = __builtin_amdgcn_mfma_f32_32x32x16_bf16(pa, vf0_, acc0, 0, 0, 0); \
    acc1 = __builtin_amdgcn_mfma_f32_32x32x16_bf16(pa, vf1_, acc1, 0, 0, 0); \
} while (0)

// Swapped QK^T with 32x32x16: S^T[kv][q]; lane: q = lq32,
// kv = kvsub*32 + (r&3) + 8*(r>>2) + 4*hi.  Softmax fully in-lane + 1 xhalf.
// s_setprio(1) wraps the two MFMA clusters (T5; +4-7% attn, m191).
#define COMPUTE32(qf, acc0, acc1, mm, ll, q0, kv0, b) do { \
    f32x16 s0_ = (f32x16)0.f, s1_ = (f32x16)0.f; \
    __builtin_amdgcn_s_setprio(1); \
    _Pragma("unroll") for (int c = 0; c < 4; ++c) { \
        bf16x8 k0_ = *(const bf16x8*)&Kl[b][swz(lq32,      c * 16 + hi * 8)]; \
        bf16x8 k1_ = *(const bf16x8*)&Kl[b][swz(32 + lq32, c * 16 + hi * 8)]; \
        s0_ = __builtin_amdgcn_mfma_f32_32x32x16_bf16(k0_, qf[c], s0_, 0, 0, 0); \
        s1_ = __builtin_amdgcn_mfma_f32_32x32x16_bf16(k1_, qf[c], s1_, 0, 0, 0); \
    } \
    __builtin_amdgcn_s_setprio(0); \
    if ((kv0) + 63 > (q0)) {   /* diagonal tile: causal mask */ \
        _Pragma("unroll") for (int r = 0; r < 16; ++r) { \
            const int kvr_ = (r & 3) + 8 * (r >> 2) + 4 * hi; \
            if ((kv0) + kvr_      > (q0) + lq32) s0_[r] = -1e30f; \
            if ((kv0) + 32 + kvr_ > (q0) + lq32) s1_[r] = -1e30f; \
        } \
    } \
    float m0_ = fmaxf(s0_[0], s1_[0]), m1_ = fmaxf(s0_[1], s1_[1]); \
    float m2_ = fmaxf(s0_[2], s1_[2]), m3_ = fmaxf(s0_[3], s1_[3]); \
    _Pragma("unroll") for (int r = 4; r < 16; r += 4) { \
        m0_ = fmaxf(m0_, fmaxf(s0_[r],     s1_[r])); \
        m1_ = fmaxf(m1_, fmaxf(s0_[r + 1], s1_[r + 1])); \
        m2_ = fmaxf(m2_, fmaxf(s0_[r + 2], s1_[r + 2])); \
        m3_ = fmaxf(m3_, fmaxf(s0_[r + 3], s1_[r + 3])); \
    } \
    float pmax_ = xhalf_max(fmaxf(fmaxf(m0_, m1_), fmaxf(m2_, m3_))); \
    if (!__all(pmax_ <= (mm) + THR)) {      /* defer-max: rare rescale */ \
        const float mn_ = fmaxf((mm), pmax_); \
        const float f_  = EXP2((mm) - mn_); \
        (ll) *= f_; \
        _Pragma("unroll") for (int r = 0; r < 16; ++r) { \
            const float fr_ = __shfl(f_, (r & 3) + 8 * (r >> 2) + 4 * hi); \
            acc0[r] *= fr_; acc1[r] *= fr_; \
        } \
        (mm) = mn_; \
    } \
    float t0_ = 0.f, t1_ = 0.f, t2_ = 0.f, t3_ = 0.f; \
    _Pragma("unroll") for (int r = 0; r < 16; r += 4) { \
        s0_[r]     = EXP2(s0_[r]     - (mm)); s1_[r]     = EXP2(s1_[r]     - (mm)); \
        s0_[r + 1] = EXP2(s0_[r + 1] - (mm)); s1_[r + 1] = EXP2(s1_[r + 1] - (mm)); \
        s0_[r + 2] = EXP2(s0_[r + 2] - (mm)); s1_[r + 2] = EXP2(s1_[r + 2] - (mm)); \
        s0_[r + 3] = EXP2(s0_[r + 3] - (mm)); s1_[r + 3] = EXP2(s1_[r + 3] - (mm)); \
        t0_ += s0_[r]     + s1_[r]; \
        t1_ += s0_[r + 1] + s1_[r + 1]; \
        t2_ += s0_[r + 2] + s1_[r + 2]; \
        t3_ += s0_[r + 3] + s1_[r + 3]; \
    } \
    (ll) += (t0_ + t1_) + (t2_ + t3_);      /* in-lane half-sum; combine at end */ \
    bf16x8 pa0_, pa1_, pa2_, pa3_; \
    MKFRAG(pa0_, s0_, 0); MKFRAG(pa1_, s0_, 8); \
    MKFRAG(pa2_, s1_, 0); MKFRAG(pa3_, s1_, 8); \
    __builtin_amdgcn_s_setprio(1); \
    PVSTEP(pa0_, 0,  acc0, acc1, b); \
    PVSTEP(pa1_, 16, acc0, acc1, b); \
    PVSTEP(pa2_, 32, acc0, acc1, b); \
    PVSTEP(pa3_, 48, acc0, acc1, b); \
    __builtin_amdgcn_s_setprio(0); \
} while (0)

// One 128-row q-tile per block, grid 64x16 = 1024 blocks, heavy-first.
__global__ __launch_bounds__(256, 2)
void attn_fwd_bf16(const short* __restrict__ Qb, const short* __restrict__ Kb,
                   const short* __restrict__ Vt, float* __restrict__ Out)
{
    const int bh   = blockIdx.x;          // 0..63 (fast dim)
    const int qt   = NQT - 1 - blockIdx.y; // heavy q-tiles dispatch first
    const int tid  = threadIdx.x;
    const int wid  = tid >> 6;
    const int lane = tid & 63;
    const int lq32 = lane & 31;
    const int hi   = lane >> 5;

    const int nkv = 2 * qt + 2;           // 64-wide kv tiles

    const short* Qp  = Qb + (size_t)bh * S_LEN * D_DIM;
    const short* Kp  = Kb + (size_t)bh * S_LEN * D_DIM;
    const short* Vtp = Vt + (size_t)bh * D_DIM * S_LEN;
    float*       Op  = Out + (size_t)bh * S_LEN * D_DIM;

    __shared__ __align__(16) short Kl[2][64 * 64];
    __shared__ __align__(16) short Vl[2][64 * 64];   // V^T tile [d][kv-permuted]

    const int q0 = qt * 128 + wid * 32;

    // Q fragments (B-operand): col q = lq32, k(d) = c*16 + hi*8 + j
    bf16x8 qf[4];
    #pragma unroll
    for (int c = 0; c < 4; ++c)
        qf[c] = *(const bf16x8*)(Qp + (size_t)(q0 + lq32) * D_DIM + c * 16 + hi * 8);

    f32x16 acc0 = (f32x16)0.f, acc1 = (f32x16)0.f;
    float m = -1e30f, l = 0.f;

    s16x4 kreg[4], vreg[4];

    ISSUE_B(0);
    WRITE_LDS_B(0);
    __syncthreads();

    for (int j = 0; j < nkv; ++j) {
        const int  kv0  = j * 64;
        const int  buf  = j & 1;
        const bool more = (j + 1) < nkv;
        if (more) ISSUE_B(j + 1);                     // loads fly under compute
        if (kv0 <= q0 + 31) COMPUTE32(qf, acc0, acc1, m, l, q0, kv0, buf);
        if (more) {                                   // single barrier per tile
            WRITE_LDS_B(buf ^ 1);
            __syncthreads();
        }
    }

    // ---- epilogue: combine half-sums, O = acc / l ----
    l = xhalf_sum(l);
    const float il = 1.f / l;
    #pragma unroll
    for (int r = 0; r < 16; ++r) {
        const int qr   = (r & 3) + 8 * (r >> 2) + 4 * hi;
        const float vl = __shfl(il, qr);
        Op[(size_t)(q0 + qr) * D_DIM + lq32]      = acc0[r] * vl;
        Op[(size_t)(q0 + qr) * D_DIM + 32 + lq32] = acc1[r] * vl;
    }
}

extern "C" void kernel_launch(void* const* d_in, const int* in_sizes, int n_in,
                              void* d_out, int out_size, void* d_ws, size_t ws_size,
                              hipStream_t stream) {
    const float* q = (const float*)d_in[0];
    const float* k = (const float*)d_in[1];
    const float* v = (const float*)d_in[2];
    // d_in[3] (causal tril mask) handled analytically.
    float* out = (float*)d_out;
    (void)in_sizes; (void)n_in; (void)out_size; (void)ws_size;

    // ws: Qb, Kb, Vt bf16 tensors (50.3 MB; harness ws verified >= this in R6)
    short* Qb = (short*)d_ws;
    short* Kb = Qb + TEN_ELEMS;
    short* Vt = Kb + TEN_ELEMS;
    cvt_qk_kernel<<<TEN_ELEMS / 8 / 256, 256, 0, stream>>>(q, k, Qb, Kb);
    vt_kernel<<<dim3(S_LEN / 64, BH), 256, 0, stream>>>(v, Vt);
    attn_fwd_bf16<<<dim3(BH, NQT), 256, 0, stream>>>(Qb, Kb, Vt, out);
}